// Round 5
// baseline (222.061 us; speedup 1.0000x reference)
//
#include <hip/hip_runtime.h>

#define NUM_HEADS 16
#define HEAD_DIM  128
#define SEQ       2048
#define KT_STRIDE 8192   // bf16 elems per k-tile group in KF/VF (16 chunks * 512)

typedef __attribute__((ext_vector_type(8))) unsigned short us8;
typedef __attribute__((ext_vector_type(8))) __bf16 bf16x8;
typedef __attribute__((ext_vector_type(4))) float f32x4;
typedef __attribute__((ext_vector_type(16))) float f32x16;
typedef __attribute__((ext_vector_type(4))) unsigned u32x4;
typedef __attribute__((ext_vector_type(2))) unsigned u32x2;

static __device__ inline unsigned short f2bf(float x) {   // RNE
    union { float f; unsigned u; } v; v.f = x;
    unsigned r = v.u + 0x7FFFu + ((v.u >> 16) & 1u);
    return (unsigned short)(r >> 16);
}
static __device__ inline unsigned pk2bf(float a, float b) {
    return (unsigned)f2bf(a) | ((unsigned)f2bf(b) << 16);
}
static __device__ inline float fast_exp2(float x) {
#if __has_builtin(__builtin_amdgcn_exp2f)
    return __builtin_amdgcn_exp2f(x);
#else
    return exp2f(x);
#endif
}
// pack hi16(clo) into lo half, hi16(chi) into hi half (both truncated bf16)
static __device__ inline unsigned pack_hi(unsigned clo, unsigned chi) {
#if __has_builtin(__builtin_amdgcn_perm)
    return __builtin_amdgcn_perm(chi, clo, 0x07060302u);
#else
    return (clo >> 16) | (chi & 0xffff0000u);
#endif
}
static __device__ inline f32x16 mfma32(us8 a, us8 b, f32x16 c) {
    return __builtin_amdgcn_mfma_f32_32x32x16_bf16(
        __builtin_bit_cast(bf16x8, a), __builtin_bit_cast(bf16x8, b), c, 0, 0, 0);
}

// ---------- pre-pass: write K and V^T in exact 32x32x16 A-fragment order ----------
// 512 blocks (2 which x 2 kh x 32 kt x 4 kvh), 32 rows each -> 2 blocks/CU
__global__ __launch_bounds__(256)
void prep_frag(const float* __restrict__ K, const float* __restrict__ V,
               unsigned short* __restrict__ KF, unsigned short* __restrict__ VF)
{
    const int bx  = (int)blockIdx.x, t = (int)threadIdx.x;
    const int which = bx & 1, khb = (bx >> 1) & 1, kt = (bx >> 2) & 31, kvh = bx >> 7;
    __shared__ __align__(16) float Ls[32][132];

    const float* src = (which ? V : K) + ((size_t)kvh * SEQ + kt * 64 + khb * 32) * HEAD_DIM;
    #pragma unroll
    for (int i = 0; i < 4; ++i) {
        const int idx = t + i * 256;
        const int r = idx >> 5, c4 = idx & 31;
        *(float4*)&Ls[r][c4 * 4] = *(const float4*)(src + (size_t)r * HEAD_DIM + c4 * 4);
    }
    __syncthreads();

    if (!which) {  // K fragments
        #pragma unroll
        for (int i = 0; i < 2; ++i) {
            const int c = t + i * 256;              // 0..511
            const int lane = c & 63, ds = (c >> 6) & 3, mat = (c >> 8) & 1;
            const int H = lane >> 5;
            const int row = lane & 31;              // local row within our 32
            const int dim = mat * 64 + ds * 16 + H * 8;
            u32x4 pk;
            #pragma unroll
            for (int jj = 0; jj < 4; ++jj)
                pk[jj] = pk2bf(Ls[row][dim + 2*jj], Ls[row][dim + 2*jj + 1]);
            *(us8*)(KF + ((size_t)(kvh * 32 + kt) * 16 + khb * 8 + mat * 4 + ds) * 512 + lane * 8)
                = __builtin_bit_cast(us8, pk);
        }
    } else {       // V^T fragments
        #pragma unroll
        for (int i = 0; i < 2; ++i) {
            const int c = t + i * 256;
            const int lane = c & 63, db = (c >> 6) & 3, ks = (c >> 8) & 1;
            const int H = lane >> 5;
            const int s0 = ks * 16 + H * 8;         // local row within our 32
            const int d  = db * 32 + (lane & 31);
            u32x4 pk;
            #pragma unroll
            for (int jj = 0; jj < 4; ++jj)
                pk[jj] = pk2bf(Ls[s0 + 2*jj][d], Ls[s0 + 2*jj + 1][d]);
            *(us8*)(VF + ((size_t)(kvh * 32 + kt) * 16 + khb * 8 + ks * 4 + db) * 512 + lane * 8)
                = __builtin_bit_cast(us8, pk);
        }
    }
}

// ---------- main: q-tile-PAIR blocks (64 q-rows / k-tile) — halves L2/L1 load bytes ----------
// R0-R4 showed dur invariant to occupancy/locality at 17 TB/s load traffic: per-CU
// vector-load delivery BW is the wall. Fix = reuse: each k-tile load feeds TWO q-tiles.
// Registers ~310/wave -> 1 wave/SIMD (occupancy proven irrelevant). Perfect balance via
// chained complementary pairs (31-ps then ps): every block runs exactly 33 bodies.
// Grid 256 = 1 block/CU; XCD pair {2k,2k+1} keeps kv-head k's KF/VF slice L2-local.
__global__ __launch_bounds__(256, 1)
void diff_attn_mfma14(const float* __restrict__ Q,
                      const unsigned short* __restrict__ KF,
                      const unsigned short* __restrict__ VF,
                      float* __restrict__ Out)
{
    __shared__ float cb[2][32][136];   // epilogue-only combine buffer
    __shared__ float rsb[2][2][32];

    const int t   = (int)threadIdx.x;
    const int wv  = t >> 6;
    const int ln  = t & 63;
    const int mat = wv >> 1;        // 0: softmax1 (dims 0..63), 1: softmax2 (64..127)
    const int kh  = wv & 1;         // k-half of the 64-k tile
    const int q   = ln & 31;        // q-col
    const int H   = ln >> 5;

    // grid 256: xcd = bx&7 (HW round-robin); head group fixed per XCD pair
    const int bx  = (int)blockIdx.x;
    const int xcd = bx & 7;
    const int u   = bx >> 3;                     // 0..31
    const int kvh = xcd >> 1;
    const int h   = kvh * 4 + (u & 3);
    const int ps  = (u >> 2) | ((xcd & 1) << 3); // 0..15 chain slot

    const unsigned short* kfb = KF + ((size_t)kvh * 32 * 16 + kh * 8 + mat * 4) * 512 + ln * 8;
    const unsigned short* vfb = VF + ((size_t)kvh * 32 * 16 + kh * 8) * 512 + ln * 8;

    const float qscale = 0.125f * 1.44269504088896340736f;  // 1/8 * log2(e)

    us8 qhiA[4], qhiB[4];
    f32x16 oA[4], oB[4];           // O^T: dim = db*32+(r&3)+8*(r>>2)+4H, q-col = q
    f32x4  rsvA, rsvB;
    us8 ka[4];
    f32x16 sA, sB;

    auto loadQ = [&](int q0c, us8 (&qhi)[4]) {
        const float* qr = Q + ((size_t)h * SEQ + q0c + q) * HEAD_DIM + mat * 64;
        #pragma unroll
        for (int ds = 0; ds < 4; ++ds) {
            const int d0 = ds * 16 + H * 8;
            float x[8];
            *(float4*)&x[0] = *(const float4*)(qr + d0);
            *(float4*)&x[4] = *(const float4*)(qr + d0 + 4);
            us8 hi8;
            #pragma unroll
            for (int j = 0; j < 8; ++j) hi8[j] = f2bf(x[j] * qscale);
            qhi[ds] = hi8;
        }
    };

    // exp2+mask rows [rbase,rbase+8) of sv, pack bf16, accumulate rsv, swap to B-frag
    auto make_bp = [&](const f32x16& sv, f32x4& rsv, int rbase, int kg0, int qg,
                       bool dmask) -> us8 {
        unsigned c0[8];
        if (dmask) {
            #pragma unroll
            for (int r = 0; r < 8; ++r) {
                const int ri = rbase + r;
                const int kg = kg0 + (ri & 3) + ((ri >> 2) << 3);
                float e = (kg <= qg) ? fast_exp2(sv[ri]) : 0.f;
                c0[r] = __builtin_bit_cast(unsigned, e);
            }
        } else {
            #pragma unroll
            for (int r = 0; r < 8; ++r)
                c0[r] = __builtin_bit_cast(unsigned, fast_exp2(sv[rbase + r]));
        }
        const unsigned pA = pack_hi(c0[0], c0[1]);
        const unsigned pB = pack_hi(c0[2], c0[3]);
        const unsigned pC = pack_hi(c0[4], c0[5]);
        const unsigned pD = pack_hi(c0[6], c0[7]);
        rsv[0] += __builtin_bit_cast(float, pA << 16);
        rsv[1] += __builtin_bit_cast(float, pA & 0xffff0000u);
        rsv[2] += __builtin_bit_cast(float, pB << 16);
        rsv[3] += __builtin_bit_cast(float, pB & 0xffff0000u);
        rsv[0] += __builtin_bit_cast(float, pC << 16);
        rsv[1] += __builtin_bit_cast(float, pC & 0xffff0000u);
        rsv[2] += __builtin_bit_cast(float, pD << 16);
        rsv[3] += __builtin_bit_cast(float, pD & 0xffff0000u);
        u32x4 bw;
#if __has_builtin(__builtin_amdgcn_permlane32_swap)
        {
            u32x2 r02 = __builtin_amdgcn_permlane32_swap(pA, pC, false, false);
            u32x2 r13 = __builtin_amdgcn_permlane32_swap(pB, pD, false, false);
            bw[0] = r02[0]; bw[1] = r13[0]; bw[2] = r02[1]; bw[3] = r13[1];
        }
#else
        {
            const unsigned x1 = H ? pA : pC;
            const unsigned x2 = H ? pB : pD;
            const unsigned t1 = (unsigned)__shfl_xor((int)x1, 32, 64);
            const unsigned t2 = (unsigned)__shfl_xor((int)x2, 32, 64);
            bw[0] = H ? t1 : pA;
            bw[1] = H ? t2 : pB;
            bw[2] = H ? pC : t1;
            bw[3] = H ? pD : t2;
        }
#endif
        return __builtin_bit_cast(us8, bw);
    };

    auto epilogue = [&](f32x16 (&o)[4], f32x4& rsv, int q0c) {
        __syncthreads();
        {
            float rsc = (rsv[0] + rsv[1]) + (rsv[2] + rsv[3]);
            rsc += __shfl_xor(rsc, 32, 64);
            if (ln < 32) rsb[mat][kh][ln] = rsc;
        }
        if (kh == 1) {
            #pragma unroll
            for (int db = 0; db < 4; ++db)
                #pragma unroll
                for (int i = 0; i < 4; ++i) {
                    float4 v = { o[db][i*4+0], o[db][i*4+1], o[db][i*4+2], o[db][i*4+3] };
                    *(float4*)&cb[mat][q][db * 32 + 8 * i + 4 * H] = v;
                }
        }
        __syncthreads();
        if (kh == 0) {
            const float l = rsb[mat][0][q] + rsb[mat][1][q];
            const float a = mat ? (0.16f / l) : (0.2f / l);
            #pragma unroll
            for (int db = 0; db < 4; ++db)
                #pragma unroll
                for (int i = 0; i < 4; ++i) {
                    float4 v = *(float4*)&cb[mat][q][db * 32 + 8 * i + 4 * H];
                    o[db][i*4+0] = (o[db][i*4+0] + v.x) * a;
                    o[db][i*4+1] = (o[db][i*4+1] + v.y) * a;
                    o[db][i*4+2] = (o[db][i*4+2] + v.z) * a;
                    o[db][i*4+3] = (o[db][i*4+3] + v.w) * a;
                }
            if (mat == 1) {
                #pragma unroll
                for (int db = 0; db < 4; ++db)
                    #pragma unroll
                    for (int i = 0; i < 4; ++i) {
                        float4 v = { o[db][i*4+0], o[db][i*4+1], o[db][i*4+2], o[db][i*4+3] };
                        *(float4*)&cb[1][q][db * 32 + 8 * i + 4 * H] = v;
                    }
            }
        }
        __syncthreads();
        if (wv == 0) {
            float* ob = Out + ((size_t)h * SEQ + q0c + q) * HEAD_DIM;
            #pragma unroll
            for (int db = 0; db < 4; ++db)
                #pragma unroll
                for (int i = 0; i < 4; ++i) {
                    float4 v = *(float4*)&cb[1][q][db * 32 + 8 * i + 4 * H];
                    float4 r;
                    r.x = o[db][i*4+0] - v.x;
                    r.y = o[db][i*4+1] - v.y;
                    r.z = o[db][i*4+2] - v.z;
                    r.w = o[db][i*4+3] - v.w;
                    *(float4*)(ob + db * 32 + 8 * i + 4 * H) = r;
                }
        }
    };

    // one chained pair: q-tiles {2p, 2p+1} (rows [64p, 64p+64)), k-tiles 0..p
    auto run_pair = [&](int p) {
        const int nseg = p + 1;
        const int q0A  = p * 64, q0B = p * 64 + 32;
        loadQ(q0A, qhiA);
        loadQ(q0B, qhiB);
        #pragma unroll
        for (int i = 0; i < 4; ++i) { oA[i] = (f32x16)0.f; oB[i] = (f32x16)0.f; }
        rsvA = (f32x4)0.f;
        rsvB = (f32x4)0.f;

        us8 vaA[8], vaB[8];
        // prologue: K/V tile 0, scores tile 0 for both q-tiles
        #pragma unroll
        for (int ds = 0; ds < 4; ++ds) ka[ds] = *(const us8*)(kfb + ds * 512);
        #pragma unroll
        for (int c4 = 0; c4 < 8; ++c4) vaA[c4] = *(const us8*)(vfb + c4 * 512);
        sA = (f32x16)0.f;
        #pragma unroll
        for (int ds = 0; ds < 4; ++ds) sA = mfma32(ka[ds], qhiA[ds], sA);
        sB = (f32x16)0.f;
        #pragma unroll
        for (int ds = 0; ds < 4; ++ds) sB = mfma32(ka[ds], qhiB[ds], sB);

        // body(j): consumes sA/sB(j), vC=V(j); loads vN<-V(j+1), ka<-K(j+1) up front;
        // rewrites sA/sB(j+1) at the end (K loads get the whole body to land).
        auto body = [&](int j, us8 (&vC)[8], us8 (&vN)[8]) {
            const bool last = (j == nseg - 1);
            if (!last) {
                const unsigned short* vb = vfb + (size_t)(j + 1) * KT_STRIDE;
                #pragma unroll
                for (int c4 = 0; c4 < 8; ++c4) vN[c4] = *(const us8*)(vb + c4 * 512);
                const unsigned short* kb = kfb + (size_t)(j + 1) * KT_STRIDE;
                #pragma unroll
                for (int ds = 0; ds < 4; ++ds) ka[ds] = *(const us8*)(kb + ds * 512);
            }
            const int kg0 = j * 64 + kh * 32 + 4 * H;
            const int qgA = q0A + q, qgB = q0B + q;

            // ks = 0 (V chunks 0..3)
            us8 bp = make_bp(sA, rsvA, 0, kg0, qgA, last);
            #pragma unroll
            for (int db = 0; db < 4; ++db) oA[db] = mfma32(vC[db], bp, oA[db]);
            bp = make_bp(sB, rsvB, 0, kg0, qgB, last);
            #pragma unroll
            for (int db = 0; db < 4; ++db) oB[db] = mfma32(vC[db], bp, oB[db]);
            // ks = 1 (V chunks 4..7)
            bp = make_bp(sA, rsvA, 8, kg0, qgA, last);
            #pragma unroll
            for (int db = 0; db < 4; ++db) oA[db] = mfma32(vC[4 + db], bp, oA[db]);
            bp = make_bp(sB, rsvB, 8, kg0, qgB, last);
            #pragma unroll
            for (int db = 0; db < 4; ++db) oB[db] = mfma32(vC[4 + db], bp, oB[db]);

            if (!last) {
                sA = (f32x16)0.f;
                #pragma unroll
                for (int ds = 0; ds < 4; ++ds) sA = mfma32(ka[ds], qhiA[ds], sA);
                sB = (f32x16)0.f;
                #pragma unroll
                for (int ds = 0; ds < 4; ++ds) sB = mfma32(ka[ds], qhiB[ds], sB);
            }
        };

        int j = 0;
        for (; j + 2 <= nseg; j += 2) {
            body(j,     vaA, vaB);
            body(j + 1, vaB, vaA);
        }
        if (j < nseg) body(j, vaA, vaB);

        epilogue(oA, rsvA, q0A);
        epilogue(oB, rsvB, q0B);
    };

    run_pair(31 - ps);   // heavy pair first (nseg = 32-ps)
    run_pair(ps);        // light pair (nseg = ps+1); total 33 bodies every block
}

extern "C" void kernel_launch(void* const* d_in, const int* in_sizes, int n_in,
                              void* d_out, int out_size, void* d_ws, size_t ws_size,
                              hipStream_t stream) {
    const float* Q = (const float*)d_in[0];
    const float* K = (const float*)d_in[1];
    const float* V = (const float*)d_in[2];
    float* Out = (float*)d_out;

    unsigned short* KF = (unsigned short*)d_ws;             // 2 MB
    unsigned short* VF = KF + (size_t)4 * SEQ * HEAD_DIM;   // 2 MB

    prep_frag<<<512, 256, 0, stream>>>(K, V, KF, VF);
    diff_attn_mfma14<<<256, 256, 0, stream>>>(Q, KF, VF, Out);
}

// Round 6
// 117.847 us; speedup vs baseline: 1.8843x; 1.8843x over previous
//
#include <hip/hip_runtime.h>

#define NUM_HEADS 16
#define HEAD_DIM  128
#define SEQ       2048
#define KT_STRIDE 8192   // bf16 elems per k-tile group in KF/VF (16 chunks * 512)

typedef __attribute__((ext_vector_type(8))) unsigned short us8;
typedef __attribute__((ext_vector_type(8))) __bf16 bf16x8;
typedef __attribute__((ext_vector_type(4))) float f32x4;
typedef __attribute__((ext_vector_type(16))) float f32x16;
typedef __attribute__((ext_vector_type(4))) unsigned u32x4;
typedef __attribute__((ext_vector_type(2))) unsigned u32x2;

static __device__ inline unsigned short f2bf(float x) {   // RNE
    union { float f; unsigned u; } v; v.f = x;
    unsigned r = v.u + 0x7FFFu + ((v.u >> 16) & 1u);
    return (unsigned short)(r >> 16);
}
static __device__ inline unsigned pk2bf(float a, float b) {
    return (unsigned)f2bf(a) | ((unsigned)f2bf(b) << 16);
}
static __device__ inline float fast_exp2(float x) {
#if __has_builtin(__builtin_amdgcn_exp2f)
    return __builtin_amdgcn_exp2f(x);
#else
    return exp2f(x);
#endif
}
// pack hi16(clo) into lo half, hi16(chi) into hi half (both truncated bf16)
static __device__ inline unsigned pack_hi(unsigned clo, unsigned chi) {
#if __has_builtin(__builtin_amdgcn_perm)
    return __builtin_amdgcn_perm(chi, clo, 0x07060302u);
#else
    return (clo >> 16) | (chi & 0xffff0000u);
#endif
}
static __device__ inline f32x16 mfma32(us8 a, us8 b, f32x16 c) {
    return __builtin_amdgcn_mfma_f32_32x32x16_bf16(
        __builtin_bit_cast(bf16x8, a), __builtin_bit_cast(bf16x8, b), c, 0, 0, 0);
}

// ---------- pre-pass: write K and V^T in exact 32x32x16 A-fragment order ----------
__global__ __launch_bounds__(256)
void prep_frag(const float* __restrict__ K, const float* __restrict__ V,
               unsigned short* __restrict__ KF, unsigned short* __restrict__ VF)
{
    const int bx  = (int)blockIdx.x, t = (int)threadIdx.x;
    const int which = bx & 1, khb = (bx >> 1) & 1, kt = (bx >> 2) & 31, kvh = bx >> 7;
    __shared__ __align__(16) float Ls[32][132];

    const float* src = (which ? V : K) + ((size_t)kvh * SEQ + kt * 64 + khb * 32) * HEAD_DIM;
    #pragma unroll
    for (int i = 0; i < 4; ++i) {
        const int idx = t + i * 256;
        const int r = idx >> 5, c4 = idx & 31;
        *(float4*)&Ls[r][c4 * 4] = *(const float4*)(src + (size_t)r * HEAD_DIM + c4 * 4);
    }
    __syncthreads();

    if (!which) {  // K fragments
        #pragma unroll
        for (int i = 0; i < 2; ++i) {
            const int c = t + i * 256;              // 0..511
            const int lane = c & 63, ds = (c >> 6) & 3, mat = (c >> 8) & 1;
            const int H = lane >> 5;
            const int row = lane & 31;
            const int dim = mat * 64 + ds * 16 + H * 8;
            u32x4 pk;
            #pragma unroll
            for (int jj = 0; jj < 4; ++jj)
                pk[jj] = pk2bf(Ls[row][dim + 2*jj], Ls[row][dim + 2*jj + 1]);
            *(us8*)(KF + ((size_t)(kvh * 32 + kt) * 16 + khb * 8 + mat * 4 + ds) * 512 + lane * 8)
                = __builtin_bit_cast(us8, pk);
        }
    } else {       // V^T fragments
        #pragma unroll
        for (int i = 0; i < 2; ++i) {
            const int c = t + i * 256;
            const int lane = c & 63, db = (c >> 6) & 3, ks = (c >> 8) & 1;
            const int H = lane >> 5;
            const int s0 = ks * 16 + H * 8;
            const int d  = db * 32 + (lane & 31);
            u32x4 pk;
            #pragma unroll
            for (int jj = 0; jj < 4; ++jj)
                pk[jj] = pk2bf(Ls[s0 + 2*jj][d], Ls[s0 + 2*jj + 1][d]);
            *(us8*)(VF + ((size_t)(kvh * 32 + kt) * 16 + khb * 8 + ks * 4 + db) * 512 + lane * 8)
                = __builtin_bit_cast(us8, pk);
        }
    }
}

// ---------- main: 8-wave q-pair blocks, K/V LDS-staged via global_load_lds ----------
// R0-R4: dur invariant to occupancy/regs/affinity at ~47us, pipes <30%, RF-fill flat at
// ~28B/cyc/CU -> vector-return path is the wall. Reroute: stage K+V tile (32KB) into LDS
// (global_load_lds, layout already linear in lane*16B), 8 waves consume via LDS pipe
// (128B/cyc). 2 q-tiles per block share each staged tile. Double-buffered, stage issued
// one body ahead, one barrier/body. Grid 256 = 1 block/CU, chained pairs = 33 bodies/block.
__global__ __launch_bounds__(512, 2)
void diff_attn_mfma15(const float* __restrict__ Q,
                      const unsigned short* __restrict__ KF,
                      const unsigned short* __restrict__ VF,
                      float* __restrict__ Out)
{
    __shared__ __align__(16) unsigned short KV[2][16384];  // 2 x (16 K-chunks + 16 V-chunks) x 512
    __shared__ float cb[2][2][32][136];                    // [qsel][mat] epilogue combine
    __shared__ float rsb[2][2][2][32];                     // [qsel][mat][kh]

    const int t    = (int)threadIdx.x;
    const int wv   = t >> 6;
    const int ln   = t & 63;
    const int qsel = wv >> 2;       // 0: q-tile A (rows +0..31), 1: q-tile B (rows +32..63)
    const int mat  = (wv >> 1) & 1; // softmax1 (dims 0..63) vs softmax2 (64..127)
    const int kh   = wv & 1;        // k-half of the 64-k tile
    const int q    = ln & 31;
    const int H    = ln >> 5;

    // grid 256 = 1 block/CU; xcd = bx&7 (HW round-robin); kv-head group per XCD pair
    const int bx  = (int)blockIdx.x;
    const int xcd = bx & 7;
    const int u   = bx >> 3;                       // 0..31
    const int kvh = xcd >> 1;
    const int h   = kvh * 4 + (u & 3);
    const int ss  = (u >> 2) | ((xcd & 1) << 3);   // chain slot 0..15

    // stage source: wave wv stages chunks wv*4..wv*4+3 (0..15 = K, 16..31 = V)
    const unsigned short* sgb = (wv < 4 ? KF : VF)
        + ((size_t)kvh * 32 * 16 + (wv & 3) * 4) * 512 + ln * 8;
    auto stage = [&](int jt, int b) {
        const unsigned short* tb = sgb + (size_t)jt * KT_STRIDE;
        #pragma unroll
        for (int i = 0; i < 4; ++i) {
            __builtin_amdgcn_global_load_lds(
                (const __attribute__((address_space(1))) unsigned int*)(tb + i * 512),
                (__attribute__((address_space(3))) unsigned int*)&KV[b][(wv * 4 + i) * 512],
                16, 0, 0);
        }
    };

    const int kbase = (kh * 8 + mat * 4) * 512;   // K chunks for this wave's role
    const int vbase = (16 + kh * 8) * 512;        // V chunks

    const float qscale = 0.125f * 1.44269504088896340736f;  // 1/8 * log2(e)

    us8 qhi[4];
    auto loadQ = [&](int q0c) {
        const float* qr = Q + ((size_t)h * SEQ + q0c + q) * HEAD_DIM + mat * 64;
        #pragma unroll
        for (int ds = 0; ds < 4; ++ds) {
            const int d0 = ds * 16 + H * 8;
            float x[8];
            *(float4*)&x[0] = *(const float4*)(qr + d0);
            *(float4*)&x[4] = *(const float4*)(qr + d0 + 4);
            us8 hi8;
            #pragma unroll
            for (int j = 0; j < 8; ++j) hi8[j] = f2bf(x[j] * qscale);
            qhi[ds] = hi8;
        }
    };

    f32x16 o[4];                   // O^T: dim = db*32+(r&3)+8*(r>>2)+4H, q-col = q
    f32x4  rsv;

    // exp2+mask rows [rbase,rbase+8), pack bf16, accumulate rsv, swap to B-frag
    auto make_bp = [&](const f32x16& sv, int rbase, int kg0, int qg, bool dmask) -> us8 {
        unsigned c0[8];
        if (dmask) {
            #pragma unroll
            for (int r = 0; r < 8; ++r) {
                const int ri = rbase + r;
                const int kg = kg0 + (ri & 3) + ((ri >> 2) << 3);
                float e = (kg <= qg) ? fast_exp2(sv[ri]) : 0.f;
                c0[r] = __builtin_bit_cast(unsigned, e);
            }
        } else {
            #pragma unroll
            for (int r = 0; r < 8; ++r)
                c0[r] = __builtin_bit_cast(unsigned, fast_exp2(sv[rbase + r]));
        }
        const unsigned pA = pack_hi(c0[0], c0[1]);
        const unsigned pB = pack_hi(c0[2], c0[3]);
        const unsigned pC = pack_hi(c0[4], c0[5]);
        const unsigned pD = pack_hi(c0[6], c0[7]);
        rsv[0] += __builtin_bit_cast(float, pA << 16);
        rsv[1] += __builtin_bit_cast(float, pA & 0xffff0000u);
        rsv[2] += __builtin_bit_cast(float, pB << 16);
        rsv[3] += __builtin_bit_cast(float, pB & 0xffff0000u);
        rsv[0] += __builtin_bit_cast(float, pC << 16);
        rsv[1] += __builtin_bit_cast(float, pC & 0xffff0000u);
        rsv[2] += __builtin_bit_cast(float, pD << 16);
        rsv[3] += __builtin_bit_cast(float, pD & 0xffff0000u);
        u32x4 bw;
#if __has_builtin(__builtin_amdgcn_permlane32_swap)
        {
            u32x2 r02 = __builtin_amdgcn_permlane32_swap(pA, pC, false, false);
            u32x2 r13 = __builtin_amdgcn_permlane32_swap(pB, pD, false, false);
            bw[0] = r02[0]; bw[1] = r13[0]; bw[2] = r02[1]; bw[3] = r13[1];
        }
#else
        {
            const unsigned x1 = H ? pA : pC;
            const unsigned x2 = H ? pB : pD;
            const unsigned t1 = (unsigned)__shfl_xor((int)x1, 32, 64);
            const unsigned t2 = (unsigned)__shfl_xor((int)x2, 32, 64);
            bw[0] = H ? t1 : pA;
            bw[1] = H ? t2 : pB;
            bw[2] = H ? pC : t1;
            bw[3] = H ? pD : t2;
        }
#endif
        return __builtin_bit_cast(us8, bw);
    };

    auto epilogue = [&](int q0c) {
        __syncthreads();
        {
            float rsc = (rsv[0] + rsv[1]) + (rsv[2] + rsv[3]);
            rsc += __shfl_xor(rsc, 32, 64);
            if (ln < 32) rsb[qsel][mat][kh][ln] = rsc;
        }
        if (kh == 1) {
            #pragma unroll
            for (int db = 0; db < 4; ++db)
                #pragma unroll
                for (int i = 0; i < 4; ++i) {
                    float4 v = { o[db][i*4+0], o[db][i*4+1], o[db][i*4+2], o[db][i*4+3] };
                    *(float4*)&cb[qsel][mat][q][db * 32 + 8 * i + 4 * H] = v;
                }
        }
        __syncthreads();
        if (kh == 0) {
            const float l = rsb[qsel][mat][0][q] + rsb[qsel][mat][1][q];
            const float a = mat ? (0.16f / l) : (0.2f / l);
            #pragma unroll
            for (int db = 0; db < 4; ++db)
                #pragma unroll
                for (int i = 0; i < 4; ++i) {
                    float4 v = *(float4*)&cb[qsel][mat][q][db * 32 + 8 * i + 4 * H];
                    o[db][i*4+0] = (o[db][i*4+0] + v.x) * a;
                    o[db][i*4+1] = (o[db][i*4+1] + v.y) * a;
                    o[db][i*4+2] = (o[db][i*4+2] + v.z) * a;
                    o[db][i*4+3] = (o[db][i*4+3] + v.w) * a;
                }
            if (mat == 1) {
                #pragma unroll
                for (int db = 0; db < 4; ++db)
                    #pragma unroll
                    for (int i = 0; i < 4; ++i) {
                        float4 v = { o[db][i*4+0], o[db][i*4+1], o[db][i*4+2], o[db][i*4+3] };
                        *(float4*)&cb[qsel][1][q][db * 32 + 8 * i + 4 * H] = v;
                    }
            }
        }
        __syncthreads();
        if (mat == 0 && kh == 0) {
            float* ob = Out + ((size_t)h * SEQ + q0c + q) * HEAD_DIM;
            #pragma unroll
            for (int db = 0; db < 4; ++db)
                #pragma unroll
                for (int i = 0; i < 4; ++i) {
                    float4 v = *(float4*)&cb[qsel][1][q][db * 32 + 8 * i + 4 * H];
                    float4 r;
                    r.x = o[db][i*4+0] - v.x;
                    r.y = o[db][i*4+1] - v.y;
                    r.z = o[db][i*4+2] - v.z;
                    r.w = o[db][i*4+3] - v.w;
                    *(float4*)(ob + db * 32 + 8 * i + 4 * H) = r;
                }
        }
    };

    int bufc = 0;

    // pair p: q-rows [64p, 64p+64), k-tiles 0..p. nextp >= 0 -> prefetch its tile 0.
    auto run_pair = [&](int p, int nextp) {
        const int nseg = p + 1;
        const int q0   = p * 64 + qsel * 32;
        loadQ(q0);
        #pragma unroll
        for (int i = 0; i < 4; ++i) o[i] = (f32x16)0.f;
        rsv = (f32x4)0.f;

        for (int j = 0; j < nseg; ++j) {
            if (j + 1 < nseg)      stage(j + 1, bufc ^ 1);
            else if (nextp >= 0)   stage(0,     bufc ^ 1);   // next pair's tile 0

            const unsigned short* bufp = KV[bufc];
            us8 kaf[4];
            #pragma unroll
            for (int ds = 0; ds < 4; ++ds)
                kaf[ds] = *(const us8*)&bufp[kbase + ds * 512 + ln * 8];
            us8 va[8];
            #pragma unroll
            for (int c = 0; c < 8; ++c)
                va[c] = *(const us8*)&bufp[vbase + c * 512 + ln * 8];

            f32x16 s = (f32x16)0.f;
            #pragma unroll
            for (int ds = 0; ds < 4; ++ds) s = mfma32(kaf[ds], qhi[ds], s);

            const bool last = (j == nseg - 1);
            const int  kg0  = j * 64 + kh * 32 + 4 * H;
            const int  qg   = q0 + q;

            us8 bp = make_bp(s, 0, kg0, qg, last);
            #pragma unroll
            for (int db = 0; db < 4; ++db) o[db] = mfma32(va[db], bp, o[db]);
            bp = make_bp(s, 8, kg0, qg, last);
            #pragma unroll
            for (int db = 0; db < 4; ++db) o[db] = mfma32(va[4 + db], bp, o[db]);

            __syncthreads();    // drains stage (vmcnt) + guards buffer reuse
            bufc ^= 1;
        }
        epilogue(p * 64 + qsel * 32);
    };

    stage(0, bufc);
    __syncthreads();

    run_pair(31 - ss, ss);   // heavy pair (32-ss bodies)
    run_pair(ss, -1);        // light pair (ss+1 bodies); 33 bodies total every block
}

extern "C" void kernel_launch(void* const* d_in, const int* in_sizes, int n_in,
                              void* d_out, int out_size, void* d_ws, size_t ws_size,
                              hipStream_t stream) {
    const float* Q = (const float*)d_in[0];
    const float* K = (const float*)d_in[1];
    const float* V = (const float*)d_in[2];
    float* Out = (float*)d_out;

    unsigned short* KF = (unsigned short*)d_ws;             // 2 MB
    unsigned short* VF = KF + (size_t)4 * SEQ * HEAD_DIM;   // 2 MB

    prep_frag<<<512, 256, 0, stream>>>(K, V, KF, VF);
    diff_attn_mfma15<<<256, 512, 0, stream>>>(Q, KF, VF, Out);
}

// Round 8
// 113.825 us; speedup vs baseline: 1.9509x; 1.0353x over previous
//
#include <hip/hip_runtime.h>

#define NUM_HEADS 16
#define HEAD_DIM  128
#define SEQ       2048
#define KT_STRIDE 8192   // bf16 elems per k-tile group in KF/VF (16 chunks * 512)

typedef __attribute__((ext_vector_type(8))) unsigned short us8;
typedef __attribute__((ext_vector_type(8))) __bf16 bf16x8;
typedef __attribute__((ext_vector_type(4))) float f32x4;
typedef __attribute__((ext_vector_type(16))) float f32x16;
typedef __attribute__((ext_vector_type(4))) unsigned u32x4;
typedef __attribute__((ext_vector_type(2))) unsigned u32x2;

static __device__ inline unsigned short f2bf(float x) {   // RNE
    union { float f; unsigned u; } v; v.f = x;
    unsigned r = v.u + 0x7FFFu + ((v.u >> 16) & 1u);
    return (unsigned short)(r >> 16);
}
static __device__ inline unsigned pk2bf(float a, float b) {
    return (unsigned)f2bf(a) | ((unsigned)f2bf(b) << 16);
}
static __device__ inline float fast_exp2(float x) {
#if __has_builtin(__builtin_amdgcn_exp2f)
    return __builtin_amdgcn_exp2f(x);
#else
    return exp2f(x);
#endif
}
// pack hi16(clo) into lo half, hi16(chi) into hi half (both truncated bf16)
static __device__ inline unsigned pack_hi(unsigned clo, unsigned chi) {
#if __has_builtin(__builtin_amdgcn_perm)
    return __builtin_amdgcn_perm(chi, clo, 0x07060302u);
#else
    return (clo >> 16) | (chi & 0xffff0000u);
#endif
}
static __device__ inline f32x16 mfma32(us8 a, us8 b, f32x16 c) {
    return __builtin_amdgcn_mfma_f32_32x32x16_bf16(
        __builtin_bit_cast(bf16x8, a), __builtin_bit_cast(bf16x8, b), c, 0, 0, 0);
}

// ---------- pre-pass: write K and V^T in exact 32x32x16 A-fragment order ----------
__global__ __launch_bounds__(256)
void prep_frag(const float* __restrict__ K, const float* __restrict__ V,
               unsigned short* __restrict__ KF, unsigned short* __restrict__ VF)
{
    const int bx  = (int)blockIdx.x, t = (int)threadIdx.x;
    const int which = bx & 1, khb = (bx >> 1) & 1, kt = (bx >> 2) & 31, kvh = bx >> 7;
    __shared__ __align__(16) float Ls[32][132];

    const float* src = (which ? V : K) + ((size_t)kvh * SEQ + kt * 64 + khb * 32) * HEAD_DIM;
    #pragma unroll
    for (int i = 0; i < 4; ++i) {
        const int idx = t + i * 256;
        const int r = idx >> 5, c4 = idx & 31;
        *(float4*)&Ls[r][c4 * 4] = *(const float4*)(src + (size_t)r * HEAD_DIM + c4 * 4);
    }
    __syncthreads();

    if (!which) {  // K fragments
        #pragma unroll
        for (int i = 0; i < 2; ++i) {
            const int c = t + i * 256;              // 0..511
            const int lane = c & 63, ds = (c >> 6) & 3, mat = (c >> 8) & 1;
            const int H = lane >> 5;
            const int row = lane & 31;
            const int dim = mat * 64 + ds * 16 + H * 8;
            u32x4 pk;
            #pragma unroll
            for (int jj = 0; jj < 4; ++jj)
                pk[jj] = pk2bf(Ls[row][dim + 2*jj], Ls[row][dim + 2*jj + 1]);
            *(us8*)(KF + ((size_t)(kvh * 32 + kt) * 16 + khb * 8 + mat * 4 + ds) * 512 + lane * 8)
                = __builtin_bit_cast(us8, pk);
        }
    } else {       // V^T fragments
        #pragma unroll
        for (int i = 0; i < 2; ++i) {
            const int c = t + i * 256;
            const int lane = c & 63, db = (c >> 6) & 3, ks = (c >> 8) & 1;
            const int H = lane >> 5;
            const int s0 = ks * 16 + H * 8;
            const int d  = db * 32 + (lane & 31);
            u32x4 pk;
            #pragma unroll
            for (int jj = 0; jj < 4; ++jj)
                pk[jj] = pk2bf(Ls[s0 + 2*jj][d], Ls[s0 + 2*jj + 1][d]);
            *(us8*)(VF + ((size_t)(kvh * 32 + kt) * 16 + khb * 8 + ks * 4 + db) * 512 + lane * 8)
                = __builtin_bit_cast(us8, pk);
        }
    }
}

// ---------- main: 8-wave q-pair blocks, LDS-staged K/V, COUNTED-vmcnt pipeline ----------
// R6 diagnosis: __syncthreads per body = vmcnt(0) drain -> stage latency serialized
// (4000 cyc/body vs ~900 of work). Fix (guide T3/T4): raw s_barrier + counted vmcnt(4)
// so next tile's stage stays in flight across the barrier; triple-buffered KV -> ONE
// barrier/body; cb aliased over KV (epilogue-only); QK chain split for MFMA ILP.
// Grid 256 = 1 block/CU, chained pairs = 33 bodies/block, XCD-affine kv-heads.
__global__ __launch_bounds__(512, 2)
void diff_attn_mfma16(const float* __restrict__ Q,
                      const unsigned short* __restrict__ KF,
                      const unsigned short* __restrict__ VF,
                      float* __restrict__ Out)
{
    __shared__ __align__(16) unsigned short KV[3][16384];  // 96 KB: 3 x (16 K + 16 V chunks) x 512
    __shared__ float rsb[2][2][2][32];                     // [qsel][mat][kh]
    float* cbf = (float*)&KV[0][0];                        // epilogue-only alias (69632 B <= 96 KB)
#define CB(qs, m, qq, ii) cbf[((((qs) * 2 + (m)) * 32 + (qq)) * 136) + (ii)]

    const int t    = (int)threadIdx.x;
    const int wv   = t >> 6;
    const int ln   = t & 63;
    const int qsel = wv >> 2;       // 0: q-tile A (rows +0..31), 1: q-tile B (rows +32..63)
    const int mat  = (wv >> 1) & 1; // softmax1 (dims 0..63) vs softmax2 (64..127)
    const int kh   = wv & 1;        // k-half of the 64-k tile
    const int q    = ln & 31;
    const int H    = ln >> 5;

    // grid 256 = 1 block/CU; xcd = bx&7 (HW round-robin); kv-head group per XCD pair
    const int bx  = (int)blockIdx.x;
    const int xcd = bx & 7;
    const int u   = bx >> 3;                       // 0..31
    const int kvh = xcd >> 1;
    const int h   = kvh * 4 + (u & 3);
    const int ss  = (u >> 2) | ((xcd & 1) << 3);   // chain slot 0..15

    // stage source: wave wv stages chunks wv*4..wv*4+3 (0..15 = K, 16..31 = V)
    const unsigned short* sgb = (wv < 4 ? KF : VF)
        + ((size_t)kvh * 32 * 16 + (wv & 3) * 4) * 512 + ln * 8;
    auto stage = [&](int jt, int b) {
        const unsigned short* tb = sgb + (size_t)jt * KT_STRIDE;
        #pragma unroll
        for (int i = 0; i < 4; ++i) {
            __builtin_amdgcn_global_load_lds(
                (const __attribute__((address_space(1))) unsigned int*)(tb + i * 512),
                (__attribute__((address_space(3))) unsigned int*)&KV[b][(wv * 4 + i) * 512],
                16, 0, 0);
        }
    };

    const int kbase = (kh * 8 + mat * 4) * 512;   // K chunks for this wave's role
    const int vbase = (16 + kh * 8) * 512;        // V chunks

    const float qscale = 0.125f * 1.44269504088896340736f;  // 1/8 * log2(e)

    us8 qhi[4];
    auto loadQ = [&](int q0c) {
        const float* qr = Q + ((size_t)h * SEQ + q0c + q) * HEAD_DIM + mat * 64;
        #pragma unroll
        for (int ds = 0; ds < 4; ++ds) {
            const int d0 = ds * 16 + H * 8;
            float x[8];
            *(float4*)&x[0] = *(const float4*)(qr + d0);
            *(float4*)&x[4] = *(const float4*)(qr + d0 + 4);
            us8 hi8;
            #pragma unroll
            for (int j = 0; j < 8; ++j) hi8[j] = f2bf(x[j] * qscale);
            qhi[ds] = hi8;
        }
    };

    f32x16 o[4];                   // O^T: dim = db*32+(r&3)+8*(r>>2)+4H, q-col = q
    f32x4  rsv;

    // exp2(sv+sw rows [rbase,rbase+8)) + mask, pack bf16, accumulate rsv, swap to B-frag
    auto make_bp = [&](const f32x16& sv, const f32x16& sw, int rbase, int kg0, int qg,
                       bool dmask) -> us8 {
        unsigned c0[8];
        if (dmask) {
            #pragma unroll
            for (int r = 0; r < 8; ++r) {
                const int ri = rbase + r;
                const int kg = kg0 + (ri & 3) + ((ri >> 2) << 3);
                float e = (kg <= qg) ? fast_exp2(sv[ri] + sw[ri]) : 0.f;
                c0[r] = __builtin_bit_cast(unsigned, e);
            }
        } else {
            #pragma unroll
            for (int r = 0; r < 8; ++r) {
                const int ri = rbase + r;
                c0[r] = __builtin_bit_cast(unsigned, fast_exp2(sv[ri] + sw[ri]));
            }
        }
        const unsigned pA = pack_hi(c0[0], c0[1]);
        const unsigned pB = pack_hi(c0[2], c0[3]);
        const unsigned pC = pack_hi(c0[4], c0[5]);
        const unsigned pD = pack_hi(c0[6], c0[7]);
        rsv[0] += __builtin_bit_cast(float, pA << 16);
        rsv[1] += __builtin_bit_cast(float, pA & 0xffff0000u);
        rsv[2] += __builtin_bit_cast(float, pB << 16);
        rsv[3] += __builtin_bit_cast(float, pB & 0xffff0000u);
        rsv[0] += __builtin_bit_cast(float, pC << 16);
        rsv[1] += __builtin_bit_cast(float, pC & 0xffff0000u);
        rsv[2] += __builtin_bit_cast(float, pD << 16);
        rsv[3] += __builtin_bit_cast(float, pD & 0xffff0000u);
        u32x4 bw;
#if __has_builtin(__builtin_amdgcn_permlane32_swap)
        {
            u32x2 r02 = __builtin_amdgcn_permlane32_swap(pA, pC, false, false);
            u32x2 r13 = __builtin_amdgcn_permlane32_swap(pB, pD, false, false);
            bw[0] = r02[0]; bw[1] = r13[0]; bw[2] = r02[1]; bw[3] = r13[1];
        }
#else
        {
            const unsigned x1 = H ? pA : pC;
            const unsigned x2 = H ? pB : pD;
            const unsigned t1 = (unsigned)__shfl_xor((int)x1, 32, 64);
            const unsigned t2 = (unsigned)__shfl_xor((int)x2, 32, 64);
            bw[0] = H ? t1 : pA;
            bw[1] = H ? t2 : pB;
            bw[2] = H ? pC : t1;
            bw[3] = H ? pD : t2;
        }
#endif
        return __builtin_bit_cast(us8, bw);
    };

    auto epilogue = [&](int q0c) {
        __syncthreads();   // all compute done; KV free -> cb alias safe
        {
            float rsc = (rsv[0] + rsv[1]) + (rsv[2] + rsv[3]);
            rsc += __shfl_xor(rsc, 32, 64);
            if (ln < 32) rsb[qsel][mat][kh][ln] = rsc;
        }
        if (kh == 1) {
            #pragma unroll
            for (int db = 0; db < 4; ++db)
                #pragma unroll
                for (int i = 0; i < 4; ++i) {
                    float4 v = { o[db][i*4+0], o[db][i*4+1], o[db][i*4+2], o[db][i*4+3] };
                    *(float4*)&CB(qsel, mat, q, db * 32 + 8 * i + 4 * H) = v;
                }
        }
        __syncthreads();
        if (kh == 0) {
            const float l = rsb[qsel][mat][0][q] + rsb[qsel][mat][1][q];
            const float a = mat ? (0.16f / l) : (0.2f / l);
            #pragma unroll
            for (int db = 0; db < 4; ++db)
                #pragma unroll
                for (int i = 0; i < 4; ++i) {
                    float4 v = *(float4*)&CB(qsel, mat, q, db * 32 + 8 * i + 4 * H);
                    o[db][i*4+0] = (o[db][i*4+0] + v.x) * a;
                    o[db][i*4+1] = (o[db][i*4+1] + v.y) * a;
                    o[db][i*4+2] = (o[db][i*4+2] + v.z) * a;
                    o[db][i*4+3] = (o[db][i*4+3] + v.w) * a;
                }
            if (mat == 1) {
                #pragma unroll
                for (int db = 0; db < 4; ++db)
                    #pragma unroll
                    for (int i = 0; i < 4; ++i) {
                        float4 v = { o[db][i*4+0], o[db][i*4+1], o[db][i*4+2], o[db][i*4+3] };
                        *(float4*)&CB(qsel, 1, q, db * 32 + 8 * i + 4 * H) = v;
                    }
            }
        }
        __syncthreads();
        if (mat == 0 && kh == 0) {
            float* ob = Out + ((size_t)h * SEQ + q0c + q) * HEAD_DIM;
            #pragma unroll
            for (int db = 0; db < 4; ++db)
                #pragma unroll
                for (int i = 0; i < 4; ++i) {
                    float4 v = *(float4*)&CB(qsel, 1, q, db * 32 + 8 * i + 4 * H);
                    float4 r;
                    r.x = o[db][i*4+0] - v.x;
                    r.y = o[db][i*4+1] - v.y;
                    r.z = o[db][i*4+2] - v.z;
                    r.w = o[db][i*4+3] - v.w;
                    *(float4*)(ob + db * 32 + 8 * i + 4 * H) = r;
                }
        }
    };

    // pair p: q-rows [64p, 64p+64), k-tiles 0..p. Triple-buffered, 1 barrier/body,
    // counted vmcnt (never 0 in the loop).
    auto run_pair = [&](int p) {
        const int nseg = p + 1;
        const int q0   = p * 64 + qsel * 32;
        loadQ(q0);
        #pragma unroll
        for (int i = 0; i < 4; ++i) o[i] = (f32x16)0.f;
        rsv = (f32x4)0.f;

        __syncthreads();                 // prior epilogue's cb reads done -> KV reusable
        stage(0, 0);
        asm volatile("s_waitcnt vmcnt(0)" ::: "memory");
        __builtin_amdgcn_sched_barrier(0);
        __builtin_amdgcn_s_barrier();
        __builtin_amdgcn_sched_barrier(0);

        int cur = 0;
        for (int j = 0; j < nseg; ++j) {
            if (j + 1 < nseg) {
                stage(j + 1, (cur + 1) % 3);             // writer is 2 barriers from last reader
                asm volatile("s_waitcnt vmcnt(4)" ::: "memory");   // tile j landed; j+1 in flight
            } else {
                asm volatile("s_waitcnt vmcnt(0)" ::: "memory");   // final tile landed
            }
            __builtin_amdgcn_sched_barrier(0);
            __builtin_amdgcn_s_barrier();                // all waves' tile-j stages visible
            __builtin_amdgcn_sched_barrier(0);

            const unsigned short* bufp = &KV[cur][0];
            us8 kaf[4];
            #pragma unroll
            for (int ds = 0; ds < 4; ++ds)
                kaf[ds] = *(const us8*)&bufp[kbase + ds * 512 + ln * 8];
            us8 va[8];
            #pragma unroll
            for (int c = 0; c < 8; ++c)
                va[c] = *(const us8*)&bufp[vbase + c * 512 + ln * 8];

            // two independent 2-deep QK chains (halves MFMA dep latency)
            f32x16 s  = (f32x16)0.f;
            f32x16 s2 = (f32x16)0.f;
            s  = mfma32(kaf[0], qhi[0], s);
            s2 = mfma32(kaf[2], qhi[2], s2);
            s  = mfma32(kaf[1], qhi[1], s);
            s2 = mfma32(kaf[3], qhi[3], s2);

            const bool last = (j == nseg - 1);
            const int  kg0  = j * 64 + kh * 32 + 4 * H;
            const int  qg   = q0 + q;

            us8 bp = make_bp(s, s2, 0, kg0, qg, last);
            #pragma unroll
            for (int db = 0; db < 4; ++db) o[db] = mfma32(va[db], bp, o[db]);
            bp = make_bp(s, s2, 8, kg0, qg, last);
            #pragma unroll
            for (int db = 0; db < 4; ++db) o[db] = mfma32(va[4 + db], bp, o[db]);

            cur = (cur + 1) % 3;
        }
        epilogue(q0);
    };

    run_pair(31 - ss);   // heavy pair (32-ss bodies)
    run_pair(ss);        // light pair (ss+1 bodies); 33 bodies total every block
#undef CB
}

extern "C" void kernel_launch(void* const* d_in, const int* in_sizes, int n_in,
                              void* d_out, int out_size, void* d_ws, size_t ws_size,
                              hipStream_t stream) {
    const float* Q = (const float*)d_in[0];
    const float* K = (const float*)d_in[1];
    const float* V = (const float*)d_in[2];
    float* Out = (float*)d_out;

    unsigned short* KF = (unsigned short*)d_ws;             // 2 MB
    unsigned short* VF = KF + (size_t)4 * SEQ * HEAD_DIM;   // 2 MB

    prep_frag<<<512, 256, 0, stream>>>(K, V, KF, VF);
    diff_attn_mfma16<<<256, 512, 0, stream>>>(Q, KF, VF, Out);
}